// Round 7
// baseline (341.692 us; speedup 1.0000x reference)
//
#include <hip/hip_runtime.h>
#include <stdint.h>

// Problem constants
#define BB 16
#define T1C 512
#define T2C 64
#define DC 768
#define HC 12
#define EC 64
#define SC 576          // T1+T2
#define QSCALE 0.35355339059327379f   // 64^-0.25

typedef __attribute__((ext_vector_type(8))) short bf16x8;   // 8 bf16 = 4 VGPRs
typedef __attribute__((ext_vector_type(4))) float f32x4;    // MFMA C/D

// ---------- bf16 helpers ----------
__device__ __forceinline__ uint16_t f2b(float f) {          // RNE
    union { float f; uint32_t i; } v; v.f = f;
    return (uint16_t)((v.i + 0x7fffu + ((v.i >> 16) & 1u)) >> 16);
}
__device__ __forceinline__ uint16_t f2bfast(float f) {      // round-half-up (cheap)
    union { float f; uint32_t i; } v; v.f = f;
    return (uint16_t)((v.i + 0x8000u) >> 16);
}
__device__ __forceinline__ uint32_t pk2(float a, float b) {
    return (uint32_t)f2b(a) | ((uint32_t)f2b(b) << 16);
}

// async global->LDS, 16B per lane; LDS dest = wave-uniform base + lane*16
__device__ __forceinline__ void gll16(const void* g, void* l) {
    __builtin_amdgcn_global_load_lds(
        (const __attribute__((address_space(1))) uint32_t*)(uintptr_t)g,
        (__attribute__((address_space(3))) uint32_t*)(uintptr_t)l, 16, 0, 0);
}

// ---------- mask layout detection (deterministic -> graph-safe) ----------
__global__ void detect(const uint32_t* __restrict__ mw, int* __restrict__ flags) {
    __shared__ int aW, aB, aL;
    if (threadIdx.x == 0) { aW = 0; aB = 0; aL = 0; }
    __syncthreads();
    int lW = 0, lB = 0, lL = 0;
    for (int i = threadIdx.x; i < 2304; i += 256) {
        uint32_t w = mw[i];
        if (w > 1u) lW = 1;
        if (((w) & 0xffu) > 1u || ((w >> 8) & 0xffu) > 1u ||
            ((w >> 16) & 0xffu) > 1u || ((w >> 24) & 0xffu) > 1u) lB = 1;
        if ((w & 0xffffu) > 1u) lL = 1;
    }
    if (lW) atomicOr(&aW, 1);
    if (lB) atomicOr(&aB, 1);
    if (lL) atomicOr(&aL, 1);
    __syncthreads();
    if (threadIdx.x == 0)
        flags[0] = (!aW) ? 0 : ((!aB) ? 1 : (aL ? 2 : 0));
}

// ---------- weight transpose + f32->bf16 ----------
// Wt[z][f][k] = W_z[k][f] bf16; z: 0..5 = W_f, 6..11 = W_i, 12 = Wu_v, 13 = Wu_l
__global__ __launch_bounds__(256) void wtrans(
    const float* __restrict__ Wf, const float* __restrict__ Wi,
    const float* __restrict__ Wuv, const float* __restrict__ Wul,
    uint16_t* __restrict__ Wt)
{
    __shared__ float tile[32][33];
    const int z = blockIdx.z;
    const float* src = (z < 6)  ? Wf + (size_t)z * DC * DC
                     : (z < 12) ? Wi + (size_t)(z - 6) * DC * DC
                     : (z == 12 ? Wuv : Wul);
    uint16_t* dst = Wt + (size_t)z * DC * DC;
    const int tx = threadIdx.x & 31, ty = threadIdx.x >> 5;
    const int k0 = blockIdx.x * 32, f0 = blockIdx.y * 32;
#pragma unroll
    for (int r = 0; r < 4; r++)
        tile[ty + r * 8][tx] = src[(size_t)(k0 + ty + r * 8) * DC + f0 + tx];
    __syncthreads();
#pragma unroll
    for (int r = 0; r < 4; r++)
        dst[(size_t)(f0 + ty + r * 8) * DC + k0 + tx] = f2b(tile[tx][ty + r * 8]);
}

// ---------- X f32 -> bf16 swizzle prepass (MFMA A-fragment order) ----------
// chunk cc (8 elems): cc = ((p*24 + kt)*4 + qd)*16 + rlid
// holds X[p*16+rlid][kt*32 + qd*8 .. +7]. A frag load for (panel p, kt) is then
// 64 lanes x contiguous 16B = one coalesced 1KB burst.
__global__ __launch_bounds__(256) void xswz(
    const float* __restrict__ Xf, const float* __restrict__ Xi,
    uint16_t* __restrict__ Of, uint16_t* __restrict__ Oi)
{
    const int nf = BB * T1C * DC / 8;
    const int ni = BB * T2C * DC / 8;
    int t = blockIdx.x * 256 + threadIdx.x;
    const float* src; uint16_t* dst; int cc;
    if (t < nf) { src = Xf; dst = Of; cc = t; }
    else        { cc = t - nf; if (cc >= ni) return; src = Xi; dst = Oi; }
    int rlid = cc & 15;
    int t2 = cc >> 4;
    int qd = t2 & 3;
    int t3 = t2 >> 2;
    int kt = t3 % 24;
    int p  = t3 / 24;
    const float* sp = src + (size_t)(p * 16 + rlid) * DC + kt * 32 + qd * 8;
    float4 a = *(const float4*)sp;
    float4 b = *(const float4*)(sp + 4);
    uint4 o;
    o.x = pk2(a.x, a.y); o.y = pk2(a.z, a.w);
    o.z = pk2(b.x, b.y); o.w = pk2(b.z, b.w);
    *(uint4*)(dst + (size_t)cc * 8) = o;
}

#define BSTR 76   // epilogue bounce stride (bf16 elems), conflict-free

// ---------- MFMA projection GEMM ----------
// A: swizzled Xs, loaded DIRECTLY global->frag (no LDS). B: gll16-staged LDS.
// Merged feats+inps launch: blockIdx.x < 64 -> feats, else inps.
// QK-matrices (vmask bit clear): P layout [k6][b][h][t][e].
// V-matrices  (vmask bit set)  : P layout [k6][b][h][e][t] (transposed store).
__global__ __launch_bounds__(256, 3) void gemm_proj_mfma(
    const uint16_t* __restrict__ Xsf, const uint16_t* __restrict__ Xsi,
    const uint16_t* __restrict__ Wt,
    const float* __restrict__ b_f, const float* __restrict__ b_i,
    uint16_t* __restrict__ Pf, uint16_t* __restrict__ Pi)
{
    __shared__ union {
        uint16_t B[128 * 32];                 // 8 KB staging
        uint16_t bounce[4][16 * BSTR];        // 9.5 KB epilogue
    } sm;
    const int tid = threadIdx.x;
    const int w = tid >> 6, l = tid & 63;
    const bool isf = (blockIdx.x < 64);
    const int mx = isf ? blockIdx.x : blockIdx.x - 64;
    const int m0 = mx * 128;
    const int T  = isf ? T1C : T2C;
    const uint16_t* Xs = isf ? Xsf : Xsi;
    const float* bias  = isf ? b_f : b_i;
    uint16_t* P        = isf ? Pf : Pi;
    const int vmask    = isf ? 0x24 : 0x22;
    const int k6 = blockIdx.y / 6, nt = blockIdx.y % 6;
    const int n0 = nt * 128;
    const uint16_t* Bsrc = Wt + (size_t)((isf ? 0 : 6) + k6) * DC * DC;

    const int lid = l & 15, qd = l >> 4;
    const int wm = w >> 1, wn = w & 1;
    const int br = l >> 2, bk = (l & 3) * 8;
    const int p0 = mx * 8 + wm * 4;           // A panel base for this wave

    f32x4 acc[4][4] = {};

    for (int kt = 0; kt < DC / 32; ++kt) {
        __syncthreads();                       // prev iter's B reads done
#pragma unroll
        for (int n = 0; n < 2; ++n) {
            int c = w * 2 + n;
            gll16(Bsrc + (size_t)(n0 + c * 16 + br) * DC + kt * 32 + bk, &sm.B[c * 512]);
        }
        bf16x8 af[4];
#pragma unroll
        for (int i = 0; i < 4; i++)
            af[i] = *(const bf16x8*)(Xs + ((size_t)((p0 + i) * 24 + kt) * 64 + l) * 8);
        __syncthreads();                       // DMA drained
        bf16x8 bf[4];
#pragma unroll
        for (int j = 0; j < 4; j++)
            bf[j] = *(const bf16x8*)&sm.B[(wn * 64 + j * 16 + lid) * 32 + qd * 8];
#pragma unroll
        for (int i = 0; i < 4; i++)
#pragma unroll
            for (int j = 0; j < 4; j++)
                acc[i][j] = __builtin_amdgcn_mfma_f32_16x16x32_bf16(af[i], bf[j], acc[i][j], 0, 0, 0);
    }

    float bv[4];
#pragma unroll
    for (int j = 0; j < 4; j++)
        bv[j] = bias[k6 * DC + n0 + wn * 64 + j * 16 + lid];
    __syncthreads();   // all waves' K-loop LDS reads done before bounce overwrite

    uint16_t* reg = sm.bounce[w];
    const int mb = m0 + wm * 64;
    const int b = mb / T, tb = mb - b * T;     // 64-row wave tile never crosses b
    const int h = nt * 2 + wn;
    const int rrow = l >> 2;                   // readback row within pass
    const int rcol = (l & 3) * 16;             // readback col chunk

    if (!((vmask >> k6) & 1)) {
        // normal [t][e]: pass p = m-rows p*16..p*16+15 (i = p)
        uint16_t* dst0 = P + ((((size_t)k6 * BB + b) * HC + h) * T + tb + rrow) * EC + rcol;
#pragma unroll
        for (int p = 0; p < 4; p++) {
#pragma unroll
            for (int j = 0; j < 4; j++)
#pragma unroll
                for (int r = 0; r < 4; r++)
                    reg[(qd * 4 + r) * BSTR + j * 16 + lid] =
                        f2b((acc[p][j][r] + bv[j]) * QSCALE);
            uint4 d0 = *(const uint4*)&reg[rrow * BSTR + rcol];
            uint4 d1 = *(const uint4*)&reg[rrow * BSTR + rcol + 8];
            uint16_t* dst = dst0 + (size_t)p * 16 * EC;
            *(uint4*)dst = d0;
            *(uint4*)(dst + 8) = d1;
        }
    } else {
        // transposed [e][t]: pass p = e-rows p*16..p*16+15 (j = p)
        uint16_t* dst0 = P + (size_t)k6 * BB * HC * T * EC
                           + (((size_t)b * HC + h) * EC + rrow) * T + tb + rcol;
#pragma unroll
        for (int p = 0; p < 4; p++) {
#pragma unroll
            for (int i = 0; i < 4; i++) {
                uint32_t w0 = pk2((acc[i][p][0] + bv[p]) * QSCALE,
                                  (acc[i][p][1] + bv[p]) * QSCALE);
                uint32_t w1 = pk2((acc[i][p][2] + bv[p]) * QSCALE,
                                  (acc[i][p][3] + bv[p]) * QSCALE);
                *(uint2*)&reg[lid * BSTR + i * 16 + qd * 4] = make_uint2(w0, w1);
            }
            uint4 d0 = *(const uint4*)&reg[rrow * BSTR + rcol];
            uint4 d1 = *(const uint4*)&reg[rrow * BSTR + rcol + 8];
            uint16_t* dst = dst0 + (size_t)p * 16 * T;
            *(uint4*)dst = d0;
            *(uint4*)(dst + 8) = d1;
        }
    }
}

// ---------- MFMA output GEMM ----------
// A = attn output, PRE-SWIZZLED in frag order (written by attn) -> direct loads.
// Merged visual+language: blockIdx.x < 64 -> visual, else language.
__global__ __launch_bounds__(256, 3) void gemm_out_mfma(
    const uint16_t* __restrict__ Osv, const uint16_t* __restrict__ Osl,
    const uint16_t* __restrict__ Wt,
    const float* __restrict__ bu_v, const float* __restrict__ bu_l,
    float* __restrict__ out)
{
    __shared__ uint16_t Bs[128 * 32];
    const int tid = threadIdx.x;
    const int w = tid >> 6, l = tid & 63;
    const bool isv = (blockIdx.x < 64);
    const int mx = isv ? blockIdx.x : blockIdx.x - 64;
    const int m0 = mx * 128;
    const int rowoff = isv ? 0 : BB * T1C;
    const uint16_t* A = isv ? Osv : Osl;
    const uint16_t* Wtm = Wt + (size_t)(isv ? 12 : 13) * DC * DC;
    const float* bias = isv ? bu_v : bu_l;
    const int n0 = blockIdx.y * 128;
    const int lid = l & 15, qd = l >> 4;
    const int wm = w >> 1, wn = w & 1;
    const int br = l >> 2, bk = (l & 3) * 8;
    const int p0 = mx * 8 + wm * 4;

    f32x4 acc[4][4] = {};

    for (int kt = 0; kt < DC / 32; ++kt) {
        __syncthreads();
#pragma unroll
        for (int n = 0; n < 2; ++n) {
            int c = w * 2 + n;
            gll16(Wtm + (size_t)(n0 + c * 16 + br) * DC + kt * 32 + bk, &Bs[c * 512]);
        }
        bf16x8 af[4];
#pragma unroll
        for (int i = 0; i < 4; i++)
            af[i] = *(const bf16x8*)(A + ((size_t)((p0 + i) * 24 + kt) * 64 + l) * 8);
        __syncthreads();
        bf16x8 bf[4];
#pragma unroll
        for (int j = 0; j < 4; j++)
            bf[j] = *(const bf16x8*)&Bs[(wn * 64 + j * 16 + lid) * 32 + qd * 8];
#pragma unroll
        for (int i = 0; i < 4; i++)
#pragma unroll
            for (int j = 0; j < 4; j++)
                acc[i][j] = __builtin_amdgcn_mfma_f32_16x16x32_bf16(af[i], bf[j], acc[i][j], 0, 0, 0);
    }

    float bv[4];
#pragma unroll
    for (int j = 0; j < 4; j++)
        bv[j] = bias[n0 + wn * 64 + j * 16 + lid];
#pragma unroll
    for (int i = 0; i < 4; i++)
#pragma unroll
        for (int j = 0; j < 4; j++)
#pragma unroll
            for (int r = 0; r < 4; r++) {
                int m = m0 + wm * 64 + i * 16 + qd * 4 + r;
                int f = n0 + wn * 64 + j * 16 + lid;
                out[(size_t)(rowoff + m) * DC + f] = acc[i][j][r] + bv[j];
            }
}

// ---------- MFMA flash attention: direct K/V frag loads, no-max softmax ----------
// K [b][h][t][e] and V^T [b][h][e][t] are read straight from L2 into MFMA
// fragments (no LDS staging, ONE barrier total). P round-trips through
// wave-local LDS. O written pre-swizzled in gemm_out's A-frag order.
__global__ __launch_bounds__(256, 3) void attn_mfma(
    const uint16_t* __restrict__ Pf,
    const uint16_t* __restrict__ Pi,
    const void* __restrict__ maskp,
    const int* __restrict__ flags,
    uint16_t* __restrict__ Osv,        // swizzled visual O (M=8192)
    uint16_t* __restrict__ Osl)        // swizzled language O (M=1024)
{
    __shared__ uint16_t Plds[4][16 * 72];   // per-wave P [q][key]
    __shared__ float    Ma[SC];
    __shared__ float    Lw[4][16];

    const int tile = blockIdx.x;
    const int bh = blockIdx.y;
    const int b = bh / HC, h = bh % HC;
    const int tid = threadIdx.x;
    const int w = tid >> 6, l = tid & 63;
    const int lid = l & 15, qd = l >> 4;

    const size_t SF = (size_t)BB * HC * T1C * EC;
    const size_t SI = (size_t)BB * HC * T2C * EC;

    const bool vis = (tile < 8);
    const uint16_t *Qa, *Qb, *K1, *K2, *V1, *V2;
    uint16_t* O; int Tq, q0;
    if (vis) { Qa = Pf + 1 * SF; Qb = Pf + 3 * SF; K1 = Pf;          K2 = Pi;
               V1 = Pf + 2 * SF; V2 = Pi + 1 * SI; O = Osv; Tq = T1C; q0 = tile * 64; }
    else     { Qa = Pi + 2 * SI; Qb = Pi + 3 * SI; K1 = Pf + 4 * SF; K2 = Pi + 4 * SI;
               V1 = Pf + 5 * SF; V2 = Pi + 5 * SI; O = Osl; Tq = T2C; q0 = 0; }

    {
        const int kind = flags[0];
        for (int i = tid; i < SC; i += 256) {
            int idx = b * SC + i;
            int mv;
            if (kind == 0)      mv = ((const uint32_t*)maskp)[idx] != 0u;
            else if (kind == 1) mv = ((const uint8_t*)maskp)[idx] != 0;
            else                mv = ((const uint16_t*)maskp)[idx] != 0;
            Ma[i] = mv ? -1e9f : 0.0f;
        }
    }
    __syncthreads();   // the only barrier: Ma visible to all

    const int q = q0 + w * 16 + lid;
    const uint16_t* Qrow = Qa + ((size_t)bh * Tq + q) * EC;
    bf16x8 qf0 = *(const bf16x8*)(Qrow + qd * 8);
    bf16x8 qf1 = *(const bf16x8*)(Qrow + 32 + qd * 8);

    f32x4 o[4];
#pragma unroll
    for (int ef = 0; ef < 4; ef++) { o[ef][0]=0.f; o[ef][1]=0.f; o[ef][2]=0.f; o[ef][3]=0.f; }
    float u[4] = {0.f, 0.f, 0.f, 0.f};

    for (int c = 0; c < 9; ++c) {
        const uint16_t *Ksrc, *Vbase; int Tkv, kofs;
        if (c < 8) {
            Ksrc = K1 + ((size_t)bh * T1C + c * 64) * EC;
            Vbase = V1 + (size_t)bh * EC * T1C; Tkv = T1C; kofs = c * 64;
        } else {
            Ksrc = K2 + (size_t)bh * T2C * EC;
            Vbase = V2 + (size_t)bh * EC * T2C; Tkv = T2C; kofs = 0;
            const uint16_t* Qrow2 = Qb + ((size_t)bh * Tq + q) * EC;  // query switch
            qf0 = *(const bf16x8*)(Qrow2 + qd * 8);
            qf1 = *(const bf16x8*)(Qrow2 + 32 + qd * 8);
        }

        const int k0 = c * 64;
        // QK^T: D[q][key], K frags direct from global
        f32x4 s[4];
#pragma unroll
        for (int sub = 0; sub < 4; sub++) {
            const uint16_t* kr = Ksrc + (size_t)(sub * 16 + lid) * EC + qd * 8;
            bf16x8 kf0 = *(const bf16x8*)kr;
            bf16x8 kf1 = *(const bf16x8*)(kr + 32);
            f32x4 z; z[0]=0.f; z[1]=0.f; z[2]=0.f; z[3]=0.f;
            z = __builtin_amdgcn_mfma_f32_16x16x32_bf16(qf0, kf0, z, 0, 0, 0);
            s[sub] = __builtin_amdgcn_mfma_f32_16x16x32_bf16(qf1, kf1, z, 0, 0, 0);
        }
        // p = exp(s + mask); accumulate row-sum; write P (C-layout -> [q][key])
#pragma unroll
        for (int sub = 0; sub < 4; sub++) {
            float mv = Ma[k0 + sub * 16 + lid];
#pragma unroll
            for (int r = 0; r < 4; r++) {
                float p = __expf(s[sub][r] + mv);
                u[r] += p;
                Plds[w][(qd * 4 + r) * 72 + sub * 16 + lid] = f2bfast(p);
            }
        }
        // PV as O^T = Vt * P^T; V frags direct from global
#pragma unroll
        for (int half = 0; half < 2; half++) {
            bf16x8 pf = *(const bf16x8*)&Plds[w][lid * 72 + half * 32 + qd * 8];
#pragma unroll
            for (int ef = 0; ef < 4; ef++) {
                bf16x8 vf = *(const bf16x8*)(Vbase + (size_t)(ef * 16 + lid) * Tkv
                                             + kofs + half * 32 + qd * 8);
                o[ef] = __builtin_amdgcn_mfma_f32_16x16x32_bf16(vf, pf, o[ef], 0, 0, 0);
            }
        }
    }

    // one-time row-sum reduction across key-lanes (bits 0-3)
#pragma unroll
    for (int d = 1; d <= 8; d <<= 1)
#pragma unroll
        for (int r = 0; r < 4; r++)
            u[r] += __shfl_xor(u[r], d, 64);
    if (lid == 0) {
#pragma unroll
        for (int r = 0; r < 4; r++) Lw[w][qd * 4 + r] = u[r];
    }
    float rl = 1.f / Lw[w][lid];   // l for this lane's query (wave-local ordering)

    // O write in gemm_out's swizzled A-frag order:
    // m = b*Tq + q; panel p = m>>4 (wave-uniform), rlid = lid.
    // col = h*64 + e, e = ef*16 + qd*4 + r  ->  kt = h*2 + (ef>>1),
    // cq = (ef&1)*2 + (qd>>1), j = (qd&1)*4 + r  -> one 8B store per ef.
    const size_t p = ((size_t)b * Tq + q0 + w * 16) >> 4;
#pragma unroll
    for (int ef = 0; ef < 4; ef++) {
        uint32_t w0 = pk2(o[ef][0] * rl, o[ef][1] * rl);
        uint32_t w1 = pk2(o[ef][2] * rl, o[ef][3] * rl);
        size_t chunk = ((p * 24 + h * 2 + (ef >> 1)) * 4 + (ef & 1) * 2 + (qd >> 1)) * 16 + lid;
        *(uint2*)(O + chunk * 8 + (qd & 1) * 4) = make_uint2(w0, w1);
    }
}

// ---------- launch ----------
extern "C" void kernel_launch(void* const* d_in, const int* in_sizes, int n_in,
                              void* d_out, int out_size, void* d_ws, size_t ws_size,
                              hipStream_t stream)
{
    const float* feats = (const float*)d_in[0];
    const float* inps  = (const float*)d_in[1];
    const void*  maskp = d_in[2];
    const float* W_f   = (const float*)d_in[3];
    const float* b_f   = (const float*)d_in[4];
    const float* W_i   = (const float*)d_in[5];
    const float* b_i   = (const float*)d_in[6];
    const float* Wu_v  = (const float*)d_in[7];
    const float* bu_v  = (const float*)d_in[8];
    const float* Wu_l  = (const float*)d_in[9];
    const float* bu_l  = (const float*)d_in[10];

    const size_t MAT = (size_t)DC * DC;               // 589824
    const size_t PF_E = 6ull * BB * HC * T1C * EC;
    const size_t PI_E = 6ull * BB * HC * T2C * EC;
    uint16_t* Wt  = (uint16_t*)d_ws;
    uint16_t* Osv = Wt;                               // reuses dead Wt[0..11]
    uint16_t* Osl = Wt + (size_t)BB * T1C * HC * EC;
    uint16_t* Pf  = Wt + 14 * MAT;
    uint16_t* Pi  = Pf + PF_E;
    int* flags    = (int*)(Pi + PI_E);

    // Swizzled bf16 X lives in d_out's first ~21 MB: d_out is only written by
    // the final gemm_out launch (stream-ordered after all Xs reads).
    uint16_t* Xsf = (uint16_t*)d_out;
    uint16_t* Xsi = Xsf + (size_t)BB * T1C * DC;

    detect<<<dim3(1), dim3(256), 0, stream>>>((const uint32_t*)maskp, flags);

    wtrans<<<dim3(24, 24, 14), dim3(256), 0, stream>>>(W_f, W_i, Wu_v, Wu_l, Wt);

    {
        int nchunks = (BB * T1C * DC + BB * T2C * DC) / 8;
        xswz<<<dim3((nchunks + 255) / 256), dim3(256), 0, stream>>>(feats, inps, Xsf, Xsi);
    }

    gemm_proj_mfma<<<dim3(72, 36), dim3(256), 0, stream>>>(
        Xsf, Xsi, Wt, b_f, b_i, Pf, Pi);

    attn_mfma<<<dim3(9, BB * HC), dim3(256), 0, stream>>>(
        Pf, Pi, maskp, flags, Osv, Osl);

    gemm_out_mfma<<<dim3(72, 6), dim3(256), 0, stream>>>(
        Osv, Osl, Wt, bu_v, bu_l, (float*)d_out);
}

// Round 8
// 266.854 us; speedup vs baseline: 1.2804x; 1.2804x over previous
//
#include <hip/hip_runtime.h>
#include <stdint.h>

// Problem constants
#define BB 16
#define T1C 512
#define T2C 64
#define DC 768
#define HC 12
#define EC 64
#define SC 576          // T1+T2
#define QSCALE 0.35355339059327379f   // 64^-0.25

typedef __attribute__((ext_vector_type(8))) short bf16x8;   // 8 bf16 = 4 VGPRs
typedef __attribute__((ext_vector_type(4))) float f32x4;    // MFMA C/D

// ---------- bf16 helpers ----------
__device__ __forceinline__ uint16_t f2b(float f) {          // RNE
    union { float f; uint32_t i; } v; v.f = f;
    return (uint16_t)((v.i + 0x7fffu + ((v.i >> 16) & 1u)) >> 16);
}
__device__ __forceinline__ uint16_t f2bfast(float f) {      // round-half-up (cheap)
    union { float f; uint32_t i; } v; v.f = f;
    return (uint16_t)((v.i + 0x8000u) >> 16);
}
__device__ __forceinline__ uint32_t pk2(float a, float b) {
    return (uint32_t)f2b(a) | ((uint32_t)f2b(b) << 16);
}

// async global->LDS, 16B per lane; LDS dest = wave-uniform base + lane*16
__device__ __forceinline__ void gll16(const void* g, void* l) {
    __builtin_amdgcn_global_load_lds(
        (const __attribute__((address_space(1))) uint32_t*)(uintptr_t)g,
        (__attribute__((address_space(3))) uint32_t*)(uintptr_t)l, 16, 0, 0);
}

// ---------- mask layout detection (deterministic -> graph-safe) ----------
__global__ void detect(const uint32_t* __restrict__ mw, int* __restrict__ flags) {
    __shared__ int aW, aB, aL;
    if (threadIdx.x == 0) { aW = 0; aB = 0; aL = 0; }
    __syncthreads();
    int lW = 0, lB = 0, lL = 0;
    for (int i = threadIdx.x; i < 2304; i += 256) {
        uint32_t w = mw[i];
        if (w > 1u) lW = 1;
        if (((w) & 0xffu) > 1u || ((w >> 8) & 0xffu) > 1u ||
            ((w >> 16) & 0xffu) > 1u || ((w >> 24) & 0xffu) > 1u) lB = 1;
        if ((w & 0xffffu) > 1u) lL = 1;
    }
    if (lW) atomicOr(&aW, 1);
    if (lB) atomicOr(&aB, 1);
    if (lL) atomicOr(&aL, 1);
    __syncthreads();
    if (threadIdx.x == 0)
        flags[0] = (!aW) ? 0 : ((!aB) ? 1 : (aL ? 2 : 0));
}

// ---------- weight transpose + f32->bf16 ----------
// Wt[z][f][k] = W_z[k][f] bf16; z: 0..5 = W_f, 6..11 = W_i, 12 = Wu_v, 13 = Wu_l
__global__ __launch_bounds__(256) void wtrans(
    const float* __restrict__ Wf, const float* __restrict__ Wi,
    const float* __restrict__ Wuv, const float* __restrict__ Wul,
    uint16_t* __restrict__ Wt)
{
    __shared__ float tile[32][33];
    const int z = blockIdx.z;
    const float* src = (z < 6)  ? Wf + (size_t)z * DC * DC
                     : (z < 12) ? Wi + (size_t)(z - 6) * DC * DC
                     : (z == 12 ? Wuv : Wul);
    uint16_t* dst = Wt + (size_t)z * DC * DC;
    const int tx = threadIdx.x & 31, ty = threadIdx.x >> 5;
    const int k0 = blockIdx.x * 32, f0 = blockIdx.y * 32;
#pragma unroll
    for (int r = 0; r < 4; r++)
        tile[ty + r * 8][tx] = src[(size_t)(k0 + ty + r * 8) * DC + f0 + tx];
    __syncthreads();
#pragma unroll
    for (int r = 0; r < 4; r++)
        dst[(size_t)(f0 + ty + r * 8) * DC + k0 + tx] = f2b(tile[tx][ty + r * 8]);
}

// ---------- X f32 -> bf16 swizzle prepass (MFMA A-fragment order) ----------
// chunk cc (8 elems): cc = ((p*24 + kt)*4 + qd)*16 + rlid
// holds X[p*16+rlid][kt*32 + qd*8 .. +7]. A frag load for (panel p, kt) is then
// 64 lanes x contiguous 16B = one coalesced 1KB burst.
__global__ __launch_bounds__(256) void xswz(
    const float* __restrict__ Xf, const float* __restrict__ Xi,
    uint16_t* __restrict__ Of, uint16_t* __restrict__ Oi)
{
    const int nf = BB * T1C * DC / 8;
    const int ni = BB * T2C * DC / 8;
    int t = blockIdx.x * 256 + threadIdx.x;
    const float* src; uint16_t* dst; int cc;
    if (t < nf) { src = Xf; dst = Of; cc = t; }
    else        { cc = t - nf; if (cc >= ni) return; src = Xi; dst = Oi; }
    int rlid = cc & 15;
    int t2 = cc >> 4;
    int qd = t2 & 3;
    int t3 = t2 >> 2;
    int kt = t3 % 24;
    int p  = t3 / 24;
    const float* sp = src + (size_t)(p * 16 + rlid) * DC + kt * 32 + qd * 8;
    float4 a = *(const float4*)sp;
    float4 b = *(const float4*)(sp + 4);
    uint4 o;
    o.x = pk2(a.x, a.y); o.y = pk2(a.z, a.w);
    o.z = pk2(b.x, b.y); o.w = pk2(b.z, b.w);
    *(uint4*)(dst + (size_t)cc * 8) = o;
}

#define BSTR 76   // epilogue bounce stride (bf16 elems), conflict-free

// ---------- MFMA projection GEMM ----------
// A: swizzled Xs, loaded DIRECTLY global->frag (coalesced 1KB bursts, no LDS).
// B: gll16-staged LDS. Merged feats+inps launch: blockIdx.x < 64 -> feats.
// QK-matrices (vmask bit clear): P layout [k6][b][h][t][e].
// V-matrices  (vmask bit set)  : P layout [k6][b][h][e][t] (transposed store).
__global__ __launch_bounds__(256, 3) void gemm_proj_mfma(
    const uint16_t* __restrict__ Xsf, const uint16_t* __restrict__ Xsi,
    const uint16_t* __restrict__ Wt,
    const float* __restrict__ b_f, const float* __restrict__ b_i,
    uint16_t* __restrict__ Pf, uint16_t* __restrict__ Pi)
{
    __shared__ union {
        uint16_t B[128 * 32];                 // 8 KB staging
        uint16_t bounce[4][16 * BSTR];        // 9.5 KB epilogue
    } sm;
    const int tid = threadIdx.x;
    const int w = tid >> 6, l = tid & 63;
    const bool isf = (blockIdx.x < 64);
    const int mx = isf ? blockIdx.x : blockIdx.x - 64;
    const int m0 = mx * 128;
    const int T  = isf ? T1C : T2C;
    const uint16_t* Xs = isf ? Xsf : Xsi;
    const float* bias  = isf ? b_f : b_i;
    uint16_t* P        = isf ? Pf : Pi;
    const int vmask    = isf ? 0x24 : 0x22;
    const int k6 = blockIdx.y / 6, nt = blockIdx.y % 6;
    const int n0 = nt * 128;
    const uint16_t* Bsrc = Wt + (size_t)((isf ? 0 : 6) + k6) * DC * DC;

    const int lid = l & 15, qd = l >> 4;
    const int wm = w >> 1, wn = w & 1;
    const int br = l >> 2, bk = (l & 3) * 8;
    const int p0 = mx * 8 + wm * 4;           // A panel base for this wave

    f32x4 acc[4][4] = {};

    for (int kt = 0; kt < DC / 32; ++kt) {
        __syncthreads();                       // prev iter's B reads done
#pragma unroll
        for (int n = 0; n < 2; ++n) {
            int c = w * 2 + n;
            gll16(Bsrc + (size_t)(n0 + c * 16 + br) * DC + kt * 32 + bk, &sm.B[c * 512]);
        }
        bf16x8 af[4];
#pragma unroll
        for (int i = 0; i < 4; i++)
            af[i] = *(const bf16x8*)(Xs + ((size_t)((p0 + i) * 24 + kt) * 64 + l) * 8);
        __syncthreads();                       // DMA drained
        bf16x8 bf[4];
#pragma unroll
        for (int j = 0; j < 4; j++)
            bf[j] = *(const bf16x8*)&sm.B[(wn * 64 + j * 16 + lid) * 32 + qd * 8];
#pragma unroll
        for (int i = 0; i < 4; i++)
#pragma unroll
            for (int j = 0; j < 4; j++)
                acc[i][j] = __builtin_amdgcn_mfma_f32_16x16x32_bf16(af[i], bf[j], acc[i][j], 0, 0, 0);
    }

    float bv[4];
#pragma unroll
    for (int j = 0; j < 4; j++)
        bv[j] = bias[k6 * DC + n0 + wn * 64 + j * 16 + lid];
    __syncthreads();   // all waves' K-loop LDS reads done before bounce overwrite

    uint16_t* reg = sm.bounce[w];
    const int mb = m0 + wm * 64;
    const int b = mb / T, tb = mb - b * T;     // 64-row wave tile never crosses b
    const int h = nt * 2 + wn;
    const int rrow = l >> 2;                   // readback row within pass
    const int rcol = (l & 3) * 16;             // readback col chunk

    if (!((vmask >> k6) & 1)) {
        // normal [t][e]: pass p = m-rows p*16..p*16+15 (i = p)
        uint16_t* dst0 = P + ((((size_t)k6 * BB + b) * HC + h) * T + tb + rrow) * EC + rcol;
#pragma unroll
        for (int p = 0; p < 4; p++) {
#pragma unroll
            for (int j = 0; j < 4; j++)
#pragma unroll
                for (int r = 0; r < 4; r++)
                    reg[(qd * 4 + r) * BSTR + j * 16 + lid] =
                        f2b((acc[p][j][r] + bv[j]) * QSCALE);
            uint4 d0 = *(const uint4*)&reg[rrow * BSTR + rcol];
            uint4 d1 = *(const uint4*)&reg[rrow * BSTR + rcol + 8];
            uint16_t* dst = dst0 + (size_t)p * 16 * EC;
            *(uint4*)dst = d0;
            *(uint4*)(dst + 8) = d1;
        }
    } else {
        // transposed [e][t]: pass p = e-rows p*16..p*16+15 (j = p)
        uint16_t* dst0 = P + (size_t)k6 * BB * HC * T * EC
                           + (((size_t)b * HC + h) * EC + rrow) * T + tb + rcol;
#pragma unroll
        for (int p = 0; p < 4; p++) {
#pragma unroll
            for (int i = 0; i < 4; i++) {
                uint32_t w0 = pk2((acc[i][p][0] + bv[p]) * QSCALE,
                                  (acc[i][p][1] + bv[p]) * QSCALE);
                uint32_t w1 = pk2((acc[i][p][2] + bv[p]) * QSCALE,
                                  (acc[i][p][3] + bv[p]) * QSCALE);
                *(uint2*)&reg[lid * BSTR + i * 16 + qd * 4] = make_uint2(w0, w1);
            }
            uint4 d0 = *(const uint4*)&reg[rrow * BSTR + rcol];
            uint4 d1 = *(const uint4*)&reg[rrow * BSTR + rcol + 8];
            uint16_t* dst = dst0 + (size_t)p * 16 * T;
            *(uint4*)dst = d0;
            *(uint4*)(dst + 8) = d1;
        }
    }
}

// ---------- MFMA output GEMM ----------
// A = attn output, PRE-SWIZZLED in frag order (written by attn) -> direct loads.
// Merged visual+language: blockIdx.x < 64 -> visual, else language.
__global__ __launch_bounds__(256, 3) void gemm_out_mfma(
    const uint16_t* __restrict__ Osv, const uint16_t* __restrict__ Osl,
    const uint16_t* __restrict__ Wt,
    const float* __restrict__ bu_v, const float* __restrict__ bu_l,
    float* __restrict__ out)
{
    __shared__ uint16_t Bs[128 * 32];
    const int tid = threadIdx.x;
    const int w = tid >> 6, l = tid & 63;
    const bool isv = (blockIdx.x < 64);
    const int mx = isv ? blockIdx.x : blockIdx.x - 64;
    const int m0 = mx * 128;
    const int rowoff = isv ? 0 : BB * T1C;
    const uint16_t* A = isv ? Osv : Osl;
    const uint16_t* Wtm = Wt + (size_t)(isv ? 12 : 13) * DC * DC;
    const float* bias = isv ? bu_v : bu_l;
    const int n0 = blockIdx.y * 128;
    const int lid = l & 15, qd = l >> 4;
    const int wm = w >> 1, wn = w & 1;
    const int br = l >> 2, bk = (l & 3) * 8;
    const int p0 = mx * 8 + wm * 4;

    f32x4 acc[4][4] = {};

    for (int kt = 0; kt < DC / 32; ++kt) {
        __syncthreads();
#pragma unroll
        for (int n = 0; n < 2; ++n) {
            int c = w * 2 + n;
            gll16(Wtm + (size_t)(n0 + c * 16 + br) * DC + kt * 32 + bk, &Bs[c * 512]);
        }
        bf16x8 af[4];
#pragma unroll
        for (int i = 0; i < 4; i++)
            af[i] = *(const bf16x8*)(A + ((size_t)((p0 + i) * 24 + kt) * 64 + l) * 8);
        __syncthreads();
        bf16x8 bf[4];
#pragma unroll
        for (int j = 0; j < 4; j++)
            bf[j] = *(const bf16x8*)&Bs[(wn * 64 + j * 16 + lid) * 32 + qd * 8];
#pragma unroll
        for (int i = 0; i < 4; i++)
#pragma unroll
            for (int j = 0; j < 4; j++)
                acc[i][j] = __builtin_amdgcn_mfma_f32_16x16x32_bf16(af[i], bf[j], acc[i][j], 0, 0, 0);
    }

    float bv[4];
#pragma unroll
    for (int j = 0; j < 4; j++)
        bv[j] = bias[n0 + wn * 64 + j * 16 + lid];
#pragma unroll
    for (int i = 0; i < 4; i++)
#pragma unroll
        for (int j = 0; j < 4; j++)
#pragma unroll
            for (int r = 0; r < 4; r++) {
                int m = m0 + wm * 64 + i * 16 + qd * 4 + r;
                int f = n0 + wn * 64 + j * 16 + lid;
                out[(size_t)(rowoff + m) * DC + f] = acc[i][j][r] + bv[j];
            }
}

// ---------- MFMA flash attention: LDS-staged K/V, no-max softmax ----------
// grid (192 bh, 9 tiles): 192%8==0 => all 9 tiles of one bh map to the SAME
// XCD (linear%8 = bh%8) for K/V L2 reuse. K staged [key][e] stride 72 via
// coalesced loads shared by all 4 waves; V^T staged [e][key]. P round-trips
// through wave-local LDS. O written pre-swizzled in gemm_out's A-frag order.
__global__ __launch_bounds__(256, 3) void attn_mfma(
    const uint16_t* __restrict__ Pf,
    const uint16_t* __restrict__ Pi,
    const void* __restrict__ maskp,
    const int* __restrict__ flags,
    uint16_t* __restrict__ Osv,        // swizzled visual O (M=8192)
    uint16_t* __restrict__ Osl)        // swizzled language O (M=1024)
{
    __shared__ uint16_t Klds[64 * 72];      // [key][e]
    __shared__ uint16_t Vlds[64 * 72];      // [e][key]
    __shared__ uint16_t Plds[4][16 * 72];   // per-wave P [q][key]
    __shared__ float    Ma[SC];
    __shared__ float    Lw[4][16];

    const int bh = blockIdx.x;
    const int tile = blockIdx.y;
    const int b = bh / HC, h = bh % HC;
    const int tid = threadIdx.x;
    const int w = tid >> 6, l = tid & 63;
    const int lid = l & 15, qd = l >> 4;

    const size_t SF = (size_t)BB * HC * T1C * EC;
    const size_t SI = (size_t)BB * HC * T2C * EC;

    const bool vis = (tile < 8);
    const uint16_t *Qa, *Qb, *K1, *K2, *V1, *V2;
    uint16_t* O; int Tq, q0;
    if (vis) { Qa = Pf + 1 * SF; Qb = Pf + 3 * SF; K1 = Pf;          K2 = Pi;
               V1 = Pf + 2 * SF; V2 = Pi + 1 * SI; O = Osv; Tq = T1C; q0 = tile * 64; }
    else     { Qa = Pi + 2 * SI; Qb = Pi + 3 * SI; K1 = Pf + 4 * SF; K2 = Pi + 4 * SI;
               V1 = Pf + 5 * SF; V2 = Pi + 5 * SI; O = Osl; Tq = T2C; q0 = 0; }

    {
        const int kind = flags[0];
        for (int i = tid; i < SC; i += 256) {
            int idx = b * SC + i;
            int mv;
            if (kind == 0)      mv = ((const uint32_t*)maskp)[idx] != 0u;
            else if (kind == 1) mv = ((const uint8_t*)maskp)[idx] != 0;
            else                mv = ((const uint16_t*)maskp)[idx] != 0;
            Ma[i] = mv ? -1e9f : 0.0f;
        }
    }

    const int q = q0 + w * 16 + lid;
    const uint16_t* Qrow = Qa + ((size_t)bh * Tq + q) * EC;
    bf16x8 qf0 = *(const bf16x8*)(Qrow + qd * 8);
    bf16x8 qf1 = *(const bf16x8*)(Qrow + 32 + qd * 8);

    f32x4 o[4];
#pragma unroll
    for (int ef = 0; ef < 4; ef++) { o[ef][0]=0.f; o[ef][1]=0.f; o[ef][2]=0.f; o[ef][3]=0.f; }
    float u[4] = {0.f, 0.f, 0.f, 0.f};

    const int skey = tid >> 2, se0 = (tid & 3) * 16;   // K stage (row, col chunk)
    const int ve = tid >> 2,  vc = tid & 3;            // V stage (e-row, key chunk)

    for (int c = 0; c < 9; ++c) {
        const uint16_t *Ksrc, *Vbase; int Tkv, kofs;
        if (c < 8) {
            Ksrc = K1 + ((size_t)bh * T1C + c * 64) * EC;
            Vbase = V1 + (size_t)bh * EC * T1C; Tkv = T1C; kofs = c * 64;
        } else {
            Ksrc = K2 + (size_t)bh * T2C * EC;
            Vbase = V2 + (size_t)bh * EC * T2C; Tkv = T2C; kofs = 0;
            const uint16_t* Qrow2 = Qb + ((size_t)bh * Tq + q) * EC;  // query switch
            qf0 = *(const bf16x8*)(Qrow2 + qd * 8);
            qf1 = *(const bf16x8*)(Qrow2 + 32 + qd * 8);
        }
        __syncthreads();   // prior chunk's K/V LDS reads complete (also covers Ma @c=0)
        *(uint4*)&Klds[skey * 72 + se0]     = *(const uint4*)(Ksrc + skey * EC + se0);
        *(uint4*)&Klds[skey * 72 + se0 + 8] = *(const uint4*)(Ksrc + skey * EC + se0 + 8);
#pragma unroll
        for (int g = 0; g < 2; g++) {
            int key0 = vc * 16 + g * 8;
            *(uint4*)&Vlds[ve * 72 + key0] =
                *(const uint4*)(Vbase + (size_t)ve * Tkv + kofs + key0);
        }
        __syncthreads();

        const int k0 = c * 64;
        // QK^T: D[q][key]
        f32x4 s[4];
#pragma unroll
        for (int sub = 0; sub < 4; sub++) {
            bf16x8 kf0 = *(const bf16x8*)&Klds[(sub * 16 + lid) * 72 + qd * 8];
            bf16x8 kf1 = *(const bf16x8*)&Klds[(sub * 16 + lid) * 72 + 32 + qd * 8];
            f32x4 z; z[0]=0.f; z[1]=0.f; z[2]=0.f; z[3]=0.f;
            z = __builtin_amdgcn_mfma_f32_16x16x32_bf16(qf0, kf0, z, 0, 0, 0);
            s[sub] = __builtin_amdgcn_mfma_f32_16x16x32_bf16(qf1, kf1, z, 0, 0, 0);
        }
        // p = exp(s + mask); accumulate row-sum; write P (C-layout -> [q][key])
#pragma unroll
        for (int sub = 0; sub < 4; sub++) {
            float mv = Ma[k0 + sub * 16 + lid];
#pragma unroll
            for (int r = 0; r < 4; r++) {
                float p = __expf(s[sub][r] + mv);
                u[r] += p;
                Plds[w][(qd * 4 + r) * 72 + sub * 16 + lid] = f2bfast(p);
            }
        }
        // PV as O^T = Vt * P^T (wave-local Plds round trip, no barrier)
#pragma unroll
        for (int half = 0; half < 2; half++) {
            bf16x8 pf = *(const bf16x8*)&Plds[w][lid * 72 + half * 32 + qd * 8];
#pragma unroll
            for (int ef = 0; ef < 4; ef++) {
                bf16x8 vf = *(const bf16x8*)&Vlds[(ef * 16 + lid) * 72 + half * 32 + qd * 8];
                o[ef] = __builtin_amdgcn_mfma_f32_16x16x32_bf16(vf, pf, o[ef], 0, 0, 0);
            }
        }
    }

    // one-time row-sum reduction across key-lanes (bits 0-3)
#pragma unroll
    for (int d = 1; d <= 8; d <<= 1)
#pragma unroll
        for (int r = 0; r < 4; r++)
            u[r] += __shfl_xor(u[r], d, 64);
    if (lid == 0) {
#pragma unroll
        for (int r = 0; r < 4; r++) Lw[w][qd * 4 + r] = u[r];
    }
    float rl = 1.f / Lw[w][lid];   // l for this lane's query (wave-local ordering)

    // O write in gemm_out's swizzled A-frag order:
    // m = b*Tq + q; panel p = m>>4 (wave-uniform), rlid = lid.
    // col = h*64 + e, e = ef*16 + qd*4 + r  ->  kt = h*2 + (ef>>1),
    // cq = (ef&1)*2 + (qd>>1), j = (qd&1)*4 + r  -> one 8B store per ef.
    const size_t p = ((size_t)b * Tq + q0 + w * 16) >> 4;
#pragma unroll
    for (int ef = 0; ef < 4; ef++) {
        uint32_t w0 = pk2(o[ef][0] * rl, o[ef][1] * rl);
        uint32_t w1 = pk2(o[ef][2] * rl, o[ef][3] * rl);
        size_t chunk = ((p * 24 + h * 2 + (ef >> 1)) * 4 + (ef & 1) * 2 + (qd >> 1)) * 16 + lid;
        *(uint2*)(O + chunk * 8 + (qd & 1) * 4) = make_uint2(w0, w1);
    }
}

// ---------- launch ----------
extern "C" void kernel_launch(void* const* d_in, const int* in_sizes, int n_in,
                              void* d_out, int out_size, void* d_ws, size_t ws_size,
                              hipStream_t stream)
{
    const float* feats = (const float*)d_in[0];
    const float* inps  = (const float*)d_in[1];
    const void*  maskp = d_in[2];
    const float* W_f   = (const float*)d_in[3];
    const float* b_f   = (const float*)d_in[4];
    const float* W_i   = (const float*)d_in[5];
    const float* b_i   = (const float*)d_in[6];
    const float* Wu_v  = (const float*)d_in[7];
    const float* bu_v  = (const float*)d_in[8];
    const float* Wu_l  = (const float*)d_in[9];
    const float* bu_l  = (const float*)d_in[10];

    const size_t MAT = (size_t)DC * DC;               // 589824
    const size_t PF_E = 6ull * BB * HC * T1C * EC;
    const size_t PI_E = 6ull * BB * HC * T2C * EC;
    uint16_t* Wt  = (uint16_t*)d_ws;
    uint16_t* Osv = Wt;                               // reuses dead Wt[0..11]
    uint16_t* Osl = Wt + (size_t)BB * T1C * HC * EC;
    uint16_t* Pf  = Wt + 14 * MAT;
    uint16_t* Pi  = Pf + PF_E;
    int* flags    = (int*)(Pi + PI_E);

    // Swizzled bf16 X lives in d_out's first ~21 MB: d_out is only written by
    // the final gemm_out launch (stream-ordered after all Xs reads).
    uint16_t* Xsf = (uint16_t*)d_out;
    uint16_t* Xsi = Xsf + (size_t)BB * T1C * DC;

    detect<<<dim3(1), dim3(256), 0, stream>>>((const uint32_t*)maskp, flags);

    wtrans<<<dim3(24, 24, 14), dim3(256), 0, stream>>>(W_f, W_i, Wu_v, Wu_l, Wt);

    {
        int nchunks = (BB * T1C * DC + BB * T2C * DC) / 8;
        xswz<<<dim3((nchunks + 255) / 256), dim3(256), 0, stream>>>(feats, inps, Xsf, Xsi);
    }

    gemm_proj_mfma<<<dim3(72, 36), dim3(256), 0, stream>>>(
        Xsf, Xsi, Wt, b_f, b_i, Pf, Pi);

    attn_mfma<<<dim3(BB * HC, 9), dim3(256), 0, stream>>>(
        Pf, Pi, maskp, flags, Osv, Osl);

    gemm_out_mfma<<<dim3(72, 6), dim3(256), 0, stream>>>(
        Osv, Osl, Wt, bu_v, bu_l, (float*)d_out);
}